// Round 1
// baseline (1744.605 us; speedup 1.0000x reference)
//
#include <hip/hip_runtime.h>
#include <stdint.h>

#define K_DIM 4096
#define N_GROUPS 32

#define BM 128
#define BN 128
#define BK 32

typedef __attribute__((ext_vector_type(4))) float f32x4;
typedef __attribute__((ext_vector_type(8))) __bf16 bf16x8;

__device__ __forceinline__ unsigned short f2bf(float f) {
    union { float f; unsigned u; } c; c.f = f;
    unsigned u = c.u;
    u += 0x7FFFu + ((u >> 16) & 1u);   // RNE
    return (unsigned short)(u >> 16);
}

// ---------- prep 1: x fp32 -> bf16 ----------
__global__ __launch_bounds__(256) void cvt_x(const float* __restrict__ x,
                                             unsigned short* __restrict__ xb,
                                             int total) {
    int i = (blockIdx.x * 256 + threadIdx.x) * 8;
    if (i >= total) return;
    f32x4 a = *(const f32x4*)(x + i);
    f32x4 b = *(const f32x4*)(x + i + 4);
    union { unsigned short u[8]; uint4 v; } o;
    o.u[0] = f2bf(a.x); o.u[1] = f2bf(a.y); o.u[2] = f2bf(a.z); o.u[3] = f2bf(a.w);
    o.u[4] = f2bf(b.x); o.u[5] = f2bf(b.y); o.u[6] = f2bf(b.z); o.u[7] = f2bf(b.w);
    *(uint4*)(xb + i) = o.v;
}

// ---------- prep 2: packed int4 -> bf16 W[N][K] ----------
__global__ __launch_bounds__(256) void dequant_w(const int* __restrict__ wp,
                                                 const float* __restrict__ sc,
                                                 unsigned short* __restrict__ wd,
                                                 int total4) {
    int idx = blockIdx.x * 256 + threadIdx.x;   // int4 (4x int32) index
    if (idx >= total4) return;
    const int4 v = ((const int4*)wp)[idx];
    int flat = idx << 2;                 // int32 index
    int n = flat >> 11;                  // / (K/2 = 2048)
    int ci = flat & 2047;                // int32 col within row
    float s = sc[(n << 5) + (ci >> 6)];  // group = (2*ci)>>7 = ci>>6
    union { unsigned short u[8]; uint4 q; } o;
    int vv[4] = { v.x, v.y, v.z, v.w };
#pragma unroll
    for (int j = 0; j < 4; ++j) {
        int e = (vv[j] & 15) - 8;
        int d = ((vv[j] >> 4) & 15) - 8;
        o.u[2 * j]     = f2bf((float)e * s);
        o.u[2 * j + 1] = f2bf((float)d * s);
    }
    *(uint4*)(wd + ((size_t)n << 12) + (ci << 1)) = o.q;
}

// ---------- async global->LDS, 16B/lane ----------
__device__ __forceinline__ void gld16(const void* g, void* l) {
    __builtin_amdgcn_global_load_lds((__attribute__((address_space(1))) void*)g,
                                     (__attribute__((address_space(3))) void*)l,
                                     16, 0, 0);
}

// ---------- main GEMM: C[M,N] = A[M,K] * B[N,K]^T (bf16 in, fp32 out) ----------
__global__ __launch_bounds__(256, 2) void gemm_bt(const unsigned short* __restrict__ A,
                                                  const unsigned short* __restrict__ B,
                                                  float* __restrict__ C,
                                                  int M, int N) {
    __shared__ __align__(16) unsigned short As[BM * BK];  // 8 KB
    __shared__ __align__(16) unsigned short Bs[BN * BK];  // 8 KB

    const int tid  = threadIdx.x;
    const int wave = tid >> 6;
    const int lane = tid & 63;
    const int m0 = blockIdx.y * BM;
    const int n0 = blockIdx.x * BN;
    const int wm = (wave >> 1) * 64;
    const int wn = (wave & 1) * 64;

    // staging: wave covers tile rows [wave*32, wave*32+32); inst j adds 16 rows
    const int srow = wave * 32 + (lane >> 2);
    const int scol = (lane & 3) * 8;      // bf16 col (16B per lane)
    const unsigned short* ag = A + (size_t)(m0 + srow) * K_DIM + scol;
    const unsigned short* bg = B + (size_t)(n0 + srow) * K_DIM + scol;
    unsigned short* al = As + wave * 1024;   // wave-uniform base; HW adds lane*16B
    unsigned short* bl = Bs + wave * 1024;

    const int fr = lane & 15;
    const int fk = (lane >> 4) * 8;

    f32x4 acc[4][4] = {};

    for (int k0 = 0; k0 < K_DIM; k0 += BK) {
        __syncthreads();
        gld16(ag + k0, al);
        gld16(ag + k0 + (size_t)16 * K_DIM, al + 512);
        gld16(bg + k0, bl);
        gld16(bg + k0 + (size_t)16 * K_DIM, bl + 512);
        __syncthreads();   // drains vmcnt -> staged data visible

        bf16x8 af[4], bf[4];
#pragma unroll
        for (int i = 0; i < 4; ++i) {
            af[i] = *(const bf16x8*)(As + (wm + i * 16 + fr) * BK + fk);
            bf[i] = *(const bf16x8*)(Bs + (wn + i * 16 + fr) * BK + fk);
        }
#pragma unroll
        for (int i = 0; i < 4; ++i)
#pragma unroll
            for (int j = 0; j < 4; ++j)
                acc[i][j] = __builtin_amdgcn_mfma_f32_16x16x32_bf16(af[i], bf[j], acc[i][j], 0, 0, 0);
    }

    const int cr = (lane >> 4) * 4;
    const int cc = lane & 15;
#pragma unroll
    for (int i = 0; i < 4; ++i) {
#pragma unroll
        for (int j = 0; j < 4; ++j) {
            float* cp = C + (size_t)(m0 + wm + i * 16 + cr) * N + (n0 + wn + j * 16 + cc);
            cp[0]            = acc[i][j].x;
            cp[(size_t)N]    = acc[i][j].y;
            cp[(size_t)N*2]  = acc[i][j].z;
            cp[(size_t)N*3]  = acc[i][j].w;
        }
    }
}

// ---------- fallback: fused on-the-fly dequant GEMM (if ws too small) ----------
__global__ __launch_bounds__(256, 2) void fused_gemm(const float* __restrict__ X,
                                                     const int* __restrict__ Wp,
                                                     const float* __restrict__ Sc,
                                                     float* __restrict__ C,
                                                     int M, int N) {
    __shared__ __align__(16) unsigned short As[BM * BK];
    __shared__ __align__(16) unsigned short Bs[BN * BK];

    const int tid  = threadIdx.x;
    const int wave = tid >> 6;
    const int lane = tid & 63;
    const int m0 = blockIdx.y * BM;
    const int n0 = blockIdx.x * BN;
    const int wm = (wave >> 1) * 64;
    const int wn = (wave & 1) * 64;

    const int fr = lane & 15;
    const int fk = (lane >> 4) * 8;

    f32x4 acc[4][4] = {};

    for (int k0 = 0; k0 < K_DIM; k0 += BK) {
        __syncthreads();
        // A: 128x32 fp32 -> bf16 LDS. 1024 float4s over 256 threads.
#pragma unroll
        for (int j = 0; j < 4; ++j) {
            int f = tid + 256 * j;
            int row = f >> 3, c4 = f & 7;
            f32x4 a = *(const f32x4*)(X + (size_t)(m0 + row) * K_DIM + k0 + c4 * 4);
            union { unsigned short u[4]; uint2 q; } o;
            o.u[0] = f2bf(a.x); o.u[1] = f2bf(a.y); o.u[2] = f2bf(a.z); o.u[3] = f2bf(a.w);
            *(uint2*)(As + row * BK + c4 * 4) = o.q;
        }
        // B: 128 rows x 16 int32 -> 128x32 bf16. 512 int4s over 256 threads.
#pragma unroll
        for (int j = 0; j < 2; ++j) {
            int g = tid + 256 * j;
            int row = g >> 2, c4 = g & 3;
            const int4 v = *(const int4*)(Wp + (size_t)(n0 + row) * (K_DIM / 2) + (k0 >> 1) + c4 * 4);
            float s = Sc[(n0 + row) * N_GROUPS + (k0 >> 7)];
            union { unsigned short u[8]; uint4 q; } o;
            int vv[4] = { v.x, v.y, v.z, v.w };
#pragma unroll
            for (int t = 0; t < 4; ++t) {
                o.u[2 * t]     = f2bf((float)((vv[t] & 15) - 8) * s);
                o.u[2 * t + 1] = f2bf((float)(((vv[t] >> 4) & 15) - 8) * s);
            }
            *(uint4*)(Bs + row * BK + c4 * 8) = o.q;
        }
        __syncthreads();

        bf16x8 af[4], bf[4];
#pragma unroll
        for (int i = 0; i < 4; ++i) {
            af[i] = *(const bf16x8*)(As + (wm + i * 16 + fr) * BK + fk);
            bf[i] = *(const bf16x8*)(Bs + (wn + i * 16 + fr) * BK + fk);
        }
#pragma unroll
        for (int i = 0; i < 4; ++i)
#pragma unroll
            for (int j = 0; j < 4; ++j)
                acc[i][j] = __builtin_amdgcn_mfma_f32_16x16x32_bf16(af[i], bf[j], acc[i][j], 0, 0, 0);
    }

    const int cr = (lane >> 4) * 4;
    const int cc = lane & 15;
#pragma unroll
    for (int i = 0; i < 4; ++i) {
#pragma unroll
        for (int j = 0; j < 4; ++j) {
            float* cp = C + (size_t)(m0 + wm + i * 16 + cr) * N + (n0 + wn + j * 16 + cc);
            cp[0]           = acc[i][j].x;
            cp[(size_t)N]   = acc[i][j].y;
            cp[(size_t)N*2] = acc[i][j].z;
            cp[(size_t)N*3] = acc[i][j].w;
        }
    }
}

extern "C" void kernel_launch(void* const* d_in, const int* in_sizes, int n_in,
                              void* d_out, int out_size, void* d_ws, size_t ws_size,
                              hipStream_t stream) {
    const float* x  = (const float*)d_in[0];
    const int*   wp = (const int*)d_in[1];
    const float* sc = (const float*)d_in[2];
    float* out = (float*)d_out;

    const int M = in_sizes[0] / K_DIM;       // 8192
    const int N = in_sizes[2] / N_GROUPS;    // 11008

    const size_t xb_bytes = (size_t)M * K_DIM * 2;   // 67 MB
    const size_t wd_bytes = (size_t)N * K_DIM * 2;   // 90 MB

    dim3 grid(N / BN, M / BM);

    if (ws_size >= xb_bytes + wd_bytes) {
        unsigned short* xb = (unsigned short*)d_ws;
        unsigned short* wd = (unsigned short*)((char*)d_ws + xb_bytes);
        int xtot = M * K_DIM;
        cvt_x<<<xtot / (256 * 8), 256, 0, stream>>>(x, xb, xtot);
        int wtot4 = N * (K_DIM / 2) / 4;
        dequant_w<<<(wtot4 + 255) / 256, 256, 0, stream>>>(wp, sc, wd, wtot4);
        gemm_bt<<<grid, 256, 0, stream>>>(xb, wd, out, M, N);
    } else {
        fused_gemm<<<grid, 256, 0, stream>>>(x, wp, sc, out, M, N);
    }
}

// Round 2
// 1296.080 us; speedup vs baseline: 1.3461x; 1.3461x over previous
//
#include <hip/hip_runtime.h>
#include <stdint.h>

#define K_DIM 4096
#define N_GROUPS 32

#define BM 128
#define BN 128
#define BK 32

typedef __attribute__((ext_vector_type(4))) float f32x4;
typedef __attribute__((ext_vector_type(8))) __bf16 bf16x8;

__device__ __forceinline__ unsigned short f2bf(float f) {
    union { float f; unsigned u; } c; c.f = f;
    unsigned u = c.u;
    u += 0x7FFFu + ((u >> 16) & 1u);   // RNE
    return (unsigned short)(u >> 16);
}

// ---------- prep 1: x fp32 -> bf16 ----------
__global__ __launch_bounds__(256) void cvt_x(const float* __restrict__ x,
                                             unsigned short* __restrict__ xb,
                                             int total) {
    int i = (blockIdx.x * 256 + threadIdx.x) * 8;
    if (i >= total) return;
    f32x4 a = *(const f32x4*)(x + i);
    f32x4 b = *(const f32x4*)(x + i + 4);
    union { unsigned short u[8]; uint4 v; } o;
    o.u[0] = f2bf(a.x); o.u[1] = f2bf(a.y); o.u[2] = f2bf(a.z); o.u[3] = f2bf(a.w);
    o.u[4] = f2bf(b.x); o.u[5] = f2bf(b.y); o.u[6] = f2bf(b.z); o.u[7] = f2bf(b.w);
    *(uint4*)(xb + i) = o.v;
}

// ---------- prep 2: packed int4 -> bf16 W[N][K] ----------
__global__ __launch_bounds__(256) void dequant_w(const int* __restrict__ wp,
                                                 const float* __restrict__ sc,
                                                 unsigned short* __restrict__ wd,
                                                 int total4) {
    int idx = blockIdx.x * 256 + threadIdx.x;   // int4 (4x int32) index
    if (idx >= total4) return;
    const int4 v = ((const int4*)wp)[idx];
    int flat = idx << 2;                 // int32 index
    int n = flat >> 11;                  // / (K/2 = 2048)
    int ci = flat & 2047;                // int32 col within row
    float s = sc[(n << 5) + (ci >> 6)];  // group = (2*ci)>>7 = ci>>6
    union { unsigned short u[8]; uint4 q; } o;
    int vv[4] = { v.x, v.y, v.z, v.w };
#pragma unroll
    for (int j = 0; j < 4; ++j) {
        int e = (vv[j] & 15) - 8;
        int d = ((vv[j] >> 4) & 15) - 8;
        o.u[2 * j]     = f2bf((float)e * s);
        o.u[2 * j + 1] = f2bf((float)d * s);
    }
    *(uint4*)(wd + ((size_t)n << 12) + (ci << 1)) = o.q;
}

// ---------- async global->LDS, 16B/lane ----------
__device__ __forceinline__ void gld16(const void* g, void* l) {
    __builtin_amdgcn_global_load_lds((__attribute__((address_space(1))) void*)g,
                                     (__attribute__((address_space(3))) void*)l,
                                     16, 0, 0);
}

// ---------- main GEMM: C[M,N] = A[M,K] * B[N,K]^T (bf16 in, fp32 out) ----------
// Grouped-swizzle 1D grid + double-buffered global_load_lds prefetch.
__global__ __launch_bounds__(256, 2) void gemm_bt(const unsigned short* __restrict__ A,
                                                  const unsigned short* __restrict__ B,
                                                  float* __restrict__ C,
                                                  int M, int N) {
    __shared__ __align__(16) unsigned short As[2][BM * BK];  // 2 x 8 KB
    __shared__ __align__(16) unsigned short Bs[2][BN * BK];  // 2 x 8 KB

    const int tid  = threadIdx.x;
    const int wave = tid >> 6;
    const int lane = tid & 63;

    // ---- grouped swizzle: G=16 tiles along M walked fast, so ~256 concurrent
    // blocks touch 16 A-tiles + 16 B-tiles (~32 MB ~= aggregate L2) ----
    const int ntn = N / BN;               // 86
    const int G = 16;                     // M/BM = 64 is divisible by 16
    const int bpg = G * ntn;              // blocks per group strip
    const int bid = blockIdx.x;
    const int g   = bid / bpg;
    const int r   = bid % bpg;
    const int tm  = g * G + (r & (G - 1));
    const int tn  = r >> 4;               // r / G

    const int m0 = tm * BM;
    const int n0 = tn * BN;
    const int wm = (wave >> 1) * 64;
    const int wn = (wave & 1) * 64;

    // staging: wave covers tile rows [wave*32, wave*32+32); 2nd inst adds 16 rows
    const int srow = wave * 32 + (lane >> 2);
    const int scol = (lane & 3) * 8;      // bf16 col (16B per lane)
    const unsigned short* ag = A + (size_t)(m0 + srow) * K_DIM + scol;
    const unsigned short* bg = B + (size_t)(n0 + srow) * K_DIM + scol;
    const int lbase = wave * 1024;        // wave-uniform base; HW adds lane*16B

    const int fr = lane & 15;
    const int fk = (lane >> 4) * 8;

    f32x4 acc[4][4] = {};

    // prologue: stage tile 0 into buffer 0
    gld16(ag, As[0] + lbase);
    gld16(ag + (size_t)16 * K_DIM, As[0] + lbase + 512);
    gld16(bg, Bs[0] + lbase);
    gld16(bg + (size_t)16 * K_DIM, Bs[0] + lbase + 512);

    int buf = 0;
    for (int k0 = 0; k0 < K_DIM; k0 += BK, buf ^= 1) {
        __syncthreads();   // drains vmcnt(0): buf[buf] staged; prior ds_reads of buf^1 done

        if (k0 + BK < K_DIM) {   // prefetch next tile into the other buffer
            const int kn = k0 + BK;
            unsigned short* al = As[buf ^ 1] + lbase;
            unsigned short* bl = Bs[buf ^ 1] + lbase;
            gld16(ag + kn, al);
            gld16(ag + kn + (size_t)16 * K_DIM, al + 512);
            gld16(bg + kn, bl);
            gld16(bg + kn + (size_t)16 * K_DIM, bl + 512);
        }

        const unsigned short* Ab = As[buf];
        const unsigned short* Bb = Bs[buf];
        bf16x8 af[4], bf[4];
#pragma unroll
        for (int i = 0; i < 4; ++i) {
            af[i] = *(const bf16x8*)(Ab + (wm + i * 16 + fr) * BK + fk);
            bf[i] = *(const bf16x8*)(Bb + (wn + i * 16 + fr) * BK + fk);
        }
#pragma unroll
        for (int i = 0; i < 4; ++i)
#pragma unroll
            for (int j = 0; j < 4; ++j)
                acc[i][j] = __builtin_amdgcn_mfma_f32_16x16x32_bf16(af[i], bf[j], acc[i][j], 0, 0, 0);
    }

    const int cr = (lane >> 4) * 4;
    const int cc = lane & 15;
#pragma unroll
    for (int i = 0; i < 4; ++i) {
#pragma unroll
        for (int j = 0; j < 4; ++j) {
            float* cp = C + (size_t)(m0 + wm + i * 16 + cr) * N + (n0 + wn + j * 16 + cc);
            cp[0]            = acc[i][j].x;
            cp[(size_t)N]    = acc[i][j].y;
            cp[(size_t)N*2]  = acc[i][j].z;
            cp[(size_t)N*3]  = acc[i][j].w;
        }
    }
}

// ---------- fallback: fused on-the-fly dequant GEMM (if ws too small) ----------
__global__ __launch_bounds__(256, 2) void fused_gemm(const float* __restrict__ X,
                                                     const int* __restrict__ Wp,
                                                     const float* __restrict__ Sc,
                                                     float* __restrict__ C,
                                                     int M, int N) {
    __shared__ __align__(16) unsigned short As[BM * BK];
    __shared__ __align__(16) unsigned short Bs[BN * BK];

    const int tid  = threadIdx.x;
    const int wave = tid >> 6;
    const int lane = tid & 63;
    const int m0 = blockIdx.y * BM;
    const int n0 = blockIdx.x * BN;
    const int wm = (wave >> 1) * 64;
    const int wn = (wave & 1) * 64;

    const int fr = lane & 15;
    const int fk = (lane >> 4) * 8;

    f32x4 acc[4][4] = {};

    for (int k0 = 0; k0 < K_DIM; k0 += BK) {
        __syncthreads();
#pragma unroll
        for (int j = 0; j < 4; ++j) {
            int f = tid + 256 * j;
            int row = f >> 3, c4 = f & 7;
            f32x4 a = *(const f32x4*)(X + (size_t)(m0 + row) * K_DIM + k0 + c4 * 4);
            union { unsigned short u[4]; uint2 q; } o;
            o.u[0] = f2bf(a.x); o.u[1] = f2bf(a.y); o.u[2] = f2bf(a.z); o.u[3] = f2bf(a.w);
            *(uint2*)(As + row * BK + c4 * 4) = o.q;
        }
#pragma unroll
        for (int j = 0; j < 2; ++j) {
            int g = tid + 256 * j;
            int row = g >> 2, c4 = g & 3;
            const int4 v = *(const int4*)(Wp + (size_t)(n0 + row) * (K_DIM / 2) + (k0 >> 1) + c4 * 4);
            float s = Sc[(n0 + row) * N_GROUPS + (k0 >> 7)];
            union { unsigned short u[8]; uint4 q; } o;
            int vv[4] = { v.x, v.y, v.z, v.w };
#pragma unroll
            for (int t = 0; t < 4; ++t) {
                o.u[2 * t]     = f2bf((float)((vv[t] & 15) - 8) * s);
                o.u[2 * t + 1] = f2bf((float)(((vv[t] >> 4) & 15) - 8) * s);
            }
            *(uint4*)(Bs + row * BK + c4 * 8) = o.q;
        }
        __syncthreads();

        bf16x8 af[4], bf[4];
#pragma unroll
        for (int i = 0; i < 4; ++i) {
            af[i] = *(const bf16x8*)(As + (wm + i * 16 + fr) * BK + fk);
            bf[i] = *(const bf16x8*)(Bs + (wn + i * 16 + fr) * BK + fk);
        }
#pragma unroll
        for (int i = 0; i < 4; ++i)
#pragma unroll
            for (int j = 0; j < 4; ++j)
                acc[i][j] = __builtin_amdgcn_mfma_f32_16x16x32_bf16(af[i], bf[j], acc[i][j], 0, 0, 0);
    }

    const int cr = (lane >> 4) * 4;
    const int cc = lane & 15;
#pragma unroll
    for (int i = 0; i < 4; ++i) {
#pragma unroll
        for (int j = 0; j < 4; ++j) {
            float* cp = C + (size_t)(m0 + wm + i * 16 + cr) * N + (n0 + wn + j * 16 + cc);
            cp[0]           = acc[i][j].x;
            cp[(size_t)N]   = acc[i][j].y;
            cp[(size_t)N*2] = acc[i][j].z;
            cp[(size_t)N*3] = acc[i][j].w;
        }
    }
}

extern "C" void kernel_launch(void* const* d_in, const int* in_sizes, int n_in,
                              void* d_out, int out_size, void* d_ws, size_t ws_size,
                              hipStream_t stream) {
    const float* x  = (const float*)d_in[0];
    const int*   wp = (const int*)d_in[1];
    const float* sc = (const float*)d_in[2];
    float* out = (float*)d_out;

    const int M = in_sizes[0] / K_DIM;       // 8192
    const int N = in_sizes[2] / N_GROUPS;    // 11008

    const size_t xb_bytes = (size_t)M * K_DIM * 2;   // 67 MB
    const size_t wd_bytes = (size_t)N * K_DIM * 2;   // 90 MB

    if (ws_size >= xb_bytes + wd_bytes) {
        unsigned short* xb = (unsigned short*)d_ws;
        unsigned short* wd = (unsigned short*)((char*)d_ws + xb_bytes);
        int xtot = M * K_DIM;
        cvt_x<<<xtot / (256 * 8), 256, 0, stream>>>(x, xb, xtot);
        int wtot4 = N * (K_DIM / 2) / 4;
        dequant_w<<<(wtot4 + 255) / 256, 256, 0, stream>>>(wp, sc, wd, wtot4);
        gemm_bt<<<(M / BM) * (N / BN), 256, 0, stream>>>(xb, wd, out, M, N);
    } else {
        dim3 grid(N / BN, M / BM);
        fused_gemm<<<grid, 256, 0, stream>>>(x, wp, sc, out, M, N);
    }
}